// Round 1
// baseline (100.396 us; speedup 1.0000x reference)
//
#include <hip/hip_runtime.h>

#define NB 2
#define SQL 256
#define NH 16
#define HD 64
#define EMB 1024

// log2(e) / sqrt(EMBED): folded into Wq so softmax = 2^(q*k)
__device__ __constant__ float kQSCALE = 1.4426950408889634f / 32.0f;

__device__ __forceinline__ float fexp2(float x) { return __builtin_amdgcn_exp2f(x); }
__device__ __forceinline__ float frcp(float x)  { return __builtin_amdgcn_rcpf(x); }

// ---------------------------------------------------------------------------
// Kernel 1: q/k/v projections. One block per (n,s). Output layout [ns][e][h]
// (h contiguous, 16 per e) so attention lane e reads 16 contiguous floats.
// Wq is pre-scaled by kQSCALE.
// ---------------------------------------------------------------------------
__global__ __launch_bounds__(256) void qkv_kernel(
    const float* __restrict__ x,
    const float* __restrict__ Wq,
    const float* __restrict__ Wk,
    const float* __restrict__ Wv,
    float* __restrict__ Q,
    float* __restrict__ K,
    float* __restrict__ V)
{
    __shared__ float wq[64 * 68];
    __shared__ float wk[64 * 68];
    __shared__ float wv[64 * 68];
    __shared__ float xs[1024];

    const int tid = threadIdx.x;
    const int ns  = blockIdx.x;

    ((float4*)xs)[tid] = ((const float4*)(x + (size_t)ns * EMB))[tid];
#pragma unroll
    for (int j = 0; j < 4; ++j) {
        const int f4 = j * 256 + tid;          // 1024 float4s per matrix
        const int e  = f4 >> 4;
        const int d4 = f4 & 15;
        float4 a = ((const float4*)Wq)[f4];
        a.x *= kQSCALE; a.y *= kQSCALE; a.z *= kQSCALE; a.w *= kQSCALE;
        *(float4*)&wq[e * 68 + d4 * 4] = a;
        *(float4*)&wk[e * 68 + d4 * 4] = ((const float4*)Wk)[f4];
        *(float4*)&wv[e * 68 + d4 * 4] = ((const float4*)Wv)[f4];
    }
    __syncthreads();

    const int e  = tid >> 2;
    const int h0 = (tid & 3) * 4;

    float aq[4] = {0.f, 0.f, 0.f, 0.f};
    float ak[4] = {0.f, 0.f, 0.f, 0.f};
    float av[4] = {0.f, 0.f, 0.f, 0.f};

#pragma unroll
    for (int d4 = 0; d4 < 16; ++d4) {
        const float4 wqv = *(const float4*)&wq[e * 68 + d4 * 4];
        const float4 wkv = *(const float4*)&wk[e * 68 + d4 * 4];
        const float4 wvv = *(const float4*)&wv[e * 68 + d4 * 4];
#pragma unroll
        for (int hh = 0; hh < 4; ++hh) {
            const float4 xv = *(const float4*)&xs[(h0 + hh) * 64 + d4 * 4];
            aq[hh] = fmaf(xv.x, wqv.x, fmaf(xv.y, wqv.y, fmaf(xv.z, wqv.z, fmaf(xv.w, wqv.w, aq[hh]))));
            ak[hh] = fmaf(xv.x, wkv.x, fmaf(xv.y, wkv.y, fmaf(xv.z, wkv.z, fmaf(xv.w, wkv.w, ak[hh]))));
            av[hh] = fmaf(xv.x, wvv.x, fmaf(xv.y, wvv.y, fmaf(xv.z, wvv.z, fmaf(xv.w, wvv.w, av[hh]))));
        }
    }
    // output offset e*16 + h0 == 4*tid, components map to h0..h0+3
    *(float4*)&Q[(size_t)ns * EMB + tid * 4] = make_float4(aq[0], aq[1], aq[2], aq[3]);
    *(float4*)&K[(size_t)ns * EMB + tid * 4] = make_float4(ak[0], ak[1], ak[2], ak[3]);
    *(float4*)&V[(size_t)ns * EMB + tid * 4] = make_float4(av[0], av[1], av[2], av[3]);
}

// ---------------------------------------------------------------------------
// Kernel 2: fused elementwise-energy -> softmax over h (16) -> sum over t.
// Lane = e (64 lanes). Each wave owns 2 s-values, each block 8 s-values and a
// 32-wide t-chunk. Partial sums combined via atomicAdd into zeroed AO.
// AO channel index = h*64 + e.
// ---------------------------------------------------------------------------
__global__ __launch_bounds__(256) void attn_kernel(
    const float* __restrict__ Q,
    const float* __restrict__ K,
    const float* __restrict__ V,
    float* __restrict__ AO)
{
    const int b    = blockIdx.x;        // 2n * 32st * 8tc = 512
    const int tc   = b & 7;
    const int st   = (b >> 3) & 31;
    const int n    = b >> 8;
    const int wave = threadIdx.x >> 6;
    const int d    = threadIdx.x & 63;  // = e
    const int s0   = st * 8 + wave * 2;

    float q0[16], q1[16], acc0[16], acc1[16];
    {
        const float4* qp0 = (const float4*)(Q + ((size_t)(n * SQL + s0) * 64 + d) * 16);
        const float4* qp1 = (const float4*)(Q + ((size_t)(n * SQL + s0 + 1) * 64 + d) * 16);
#pragma unroll
        for (int j = 0; j < 4; ++j) {
            const float4 a = qp0[j];
            q0[4 * j + 0] = a.x; q0[4 * j + 1] = a.y; q0[4 * j + 2] = a.z; q0[4 * j + 3] = a.w;
            const float4 c = qp1[j];
            q1[4 * j + 0] = c.x; q1[4 * j + 1] = c.y; q1[4 * j + 2] = c.z; q1[4 * j + 3] = c.w;
        }
    }
#pragma unroll
    for (int h = 0; h < 16; ++h) { acc0[h] = 0.f; acc1[h] = 0.f; }

    const int t0 = tc * 32;
    for (int tt = 0; tt < 32; ++tt) {
        const int t = t0 + tt;
        const float4* kp = (const float4*)(K + ((size_t)(n * SQL + t) * 64 + d) * 16);
        const float4* vp = (const float4*)(V + ((size_t)(n * SQL + t) * 64 + d) * 16);
        float kv[16], vv[16];
#pragma unroll
        for (int j = 0; j < 4; ++j) {
            const float4 a = kp[j];
            kv[4 * j + 0] = a.x; kv[4 * j + 1] = a.y; kv[4 * j + 2] = a.z; kv[4 * j + 3] = a.w;
            const float4 c = vp[j];
            vv[4 * j + 0] = c.x; vv[4 * j + 1] = c.y; vv[4 * j + 2] = c.z; vv[4 * j + 3] = c.w;
        }
        // ---- s0 ----
        {
            float p[16];
#pragma unroll
            for (int h = 0; h < 16; ++h) p[h] = fexp2(q0[h] * kv[h]);
            float u0 = (p[0] + p[8])  + (p[4] + p[12]);
            float u1 = (p[1] + p[9])  + (p[5] + p[13]);
            float u2 = (p[2] + p[10]) + (p[6] + p[14]);
            float u3 = (p[3] + p[11]) + (p[7] + p[15]);
            const float rs = frcp((u0 + u1) + (u2 + u3));
#pragma unroll
            for (int h = 0; h < 16; ++h) acc0[h] = fmaf(p[h] * rs, vv[h], acc0[h]);
        }
        // ---- s1 ----
        {
            float p[16];
#pragma unroll
            for (int h = 0; h < 16; ++h) p[h] = fexp2(q1[h] * kv[h]);
            float u0 = (p[0] + p[8])  + (p[4] + p[12]);
            float u1 = (p[1] + p[9])  + (p[5] + p[13]);
            float u2 = (p[2] + p[10]) + (p[6] + p[14]);
            float u3 = (p[3] + p[11]) + (p[7] + p[15]);
            const float rs = frcp((u0 + u1) + (u2 + u3));
#pragma unroll
            for (int h = 0; h < 16; ++h) acc1[h] = fmaf(p[h] * rs, vv[h], acc1[h]);
        }
    }

    float* ao0 = AO + (size_t)(n * SQL + s0) * EMB + d;
    float* ao1 = AO + (size_t)(n * SQL + s0 + 1) * EMB + d;
#pragma unroll
    for (int h = 0; h < 16; ++h) {
        atomicAdd(ao0 + h * 64, acc0[h]);
        atomicAdd(ao1 + h * 64, acc1[h]);
    }
}

// ---------------------------------------------------------------------------
// Kernel 3: out = AO @ Wo^T (f32 vector GEMM, 64x64 tile, k-split 4).
// Writes deterministic partials P[kc]; reduce_kernel sums + bias.
// ---------------------------------------------------------------------------
__global__ __launch_bounds__(256) void proj_kernel(
    const float* __restrict__ A,
    const float* __restrict__ Wo,
    float* __restrict__ P)
{
    __shared__ float As[32][64];
    __shared__ float Ws[32][64];

    const int b  = blockIdx.x;          // 8rt * 16jt * 4kc = 512
    const int kc = b & 3;
    const int jt = (b >> 2) & 15;
    const int rt = b >> 6;
    const int tid = threadIdx.x;
    const int tx = tid & 15;
    const int ty = tid >> 4;
    const int r0 = rt * 64, j0 = jt * 64, k0 = kc * 256;

    float c[4][4];
#pragma unroll
    for (int i = 0; i < 4; ++i)
#pragma unroll
        for (int j = 0; j < 4; ++j) c[i][j] = 0.f;

    for (int kt = 0; kt < 8; ++kt) {
        const int kb = k0 + kt * 32;
        __syncthreads();
#pragma unroll
        for (int it = 0; it < 2; ++it) {
            const int f   = it * 256 + tid;    // 512 float4s per matrix tile
            const int row = f >> 3;
            const int kq  = f & 7;
            const float4 a = *(const float4*)&A[(size_t)(r0 + row) * EMB + kb + kq * 4];
            As[kq * 4 + 0][row] = a.x;
            As[kq * 4 + 1][row] = a.y;
            As[kq * 4 + 2][row] = a.z;
            As[kq * 4 + 3][row] = a.w;
            const float4 w = *(const float4*)&Wo[(size_t)(j0 + row) * EMB + kb + kq * 4];
            Ws[kq * 4 + 0][row] = w.x;
            Ws[kq * 4 + 1][row] = w.y;
            Ws[kq * 4 + 2][row] = w.z;
            Ws[kq * 4 + 3][row] = w.w;
        }
        __syncthreads();
#pragma unroll
        for (int kk = 0; kk < 32; ++kk) {
            const float4 a4 = *(const float4*)&As[kk][ty * 4];
            const float4 w4 = *(const float4*)&Ws[kk][tx * 4];
            c[0][0] = fmaf(a4.x, w4.x, c[0][0]); c[0][1] = fmaf(a4.x, w4.y, c[0][1]);
            c[0][2] = fmaf(a4.x, w4.z, c[0][2]); c[0][3] = fmaf(a4.x, w4.w, c[0][3]);
            c[1][0] = fmaf(a4.y, w4.x, c[1][0]); c[1][1] = fmaf(a4.y, w4.y, c[1][1]);
            c[1][2] = fmaf(a4.y, w4.z, c[1][2]); c[1][3] = fmaf(a4.y, w4.w, c[1][3]);
            c[2][0] = fmaf(a4.z, w4.x, c[2][0]); c[2][1] = fmaf(a4.z, w4.y, c[2][1]);
            c[2][2] = fmaf(a4.z, w4.z, c[2][2]); c[2][3] = fmaf(a4.z, w4.w, c[2][3]);
            c[3][0] = fmaf(a4.w, w4.x, c[3][0]); c[3][1] = fmaf(a4.w, w4.y, c[3][1]);
            c[3][2] = fmaf(a4.w, w4.z, c[3][2]); c[3][3] = fmaf(a4.w, w4.w, c[3][3]);
        }
    }

    float* p = P + (size_t)kc * 524288;
#pragma unroll
    for (int rr = 0; rr < 4; ++rr) {
        *(float4*)&p[(size_t)(r0 + ty * 4 + rr) * EMB + j0 + tx * 4] =
            make_float4(c[rr][0], c[rr][1], c[rr][2], c[rr][3]);
    }
}

__global__ __launch_bounds__(256) void reduce_kernel(
    const float* __restrict__ P,
    const float* __restrict__ bo,
    float* __restrict__ out)
{
    const int f4 = blockIdx.x * 256 + threadIdx.x;   // 131072 float4s
    const float4* P4 = (const float4*)P;
    const float4 a = P4[f4];
    const float4 b = P4[131072 + f4];
    const float4 c = P4[262144 + f4];
    const float4 d = P4[393216 + f4];
    const float4 bb = ((const float4*)bo)[f4 & 255];
    float4 o;
    o.x = ((a.x + b.x) + (c.x + d.x)) + bb.x;
    o.y = ((a.y + b.y) + (c.y + d.y)) + bb.y;
    o.z = ((a.z + b.z) + (c.z + d.z)) + bb.z;
    o.w = ((a.w + b.w) + (c.w + d.w)) + bb.w;
    ((float4*)out)[f4] = o;
}

extern "C" void kernel_launch(void* const* d_in, const int* in_sizes, int n_in,
                              void* d_out, int out_size, void* d_ws, size_t ws_size,
                              hipStream_t stream)
{
    const float* x  = (const float*)d_in[0];
    const float* Wq = (const float*)d_in[1];
    const float* Wk = (const float*)d_in[2];
    const float* Wv = (const float*)d_in[3];
    const float* Wo = (const float*)d_in[4];
    const float* bo = (const float*)d_in[5];

    float* ws = (float*)d_ws;
    float* Q  = ws;                 // 524288 floats
    float* K  = ws + 524288;        // 524288
    float* V  = ws + 1048576;       // 524288
    float* AO = ws + 1572864;       // 524288
    float* P  = ws + 2097152;       // 4 * 524288

    hipMemsetAsync(AO, 0, 524288 * sizeof(float), stream);
    qkv_kernel<<<512, 256, 0, stream>>>(x, Wq, Wk, Wv, Q, K, V);
    attn_kernel<<<512, 256, 0, stream>>>(Q, K, V, AO);
    proj_kernel<<<512, 256, 0, stream>>>(AO, Wo, P);
    reduce_kernel<<<512, 256, 0, stream>>>(P, bo, (float*)d_out);
}